// Round 11
// baseline (1007.161 us; speedup 1.0000x reference)
//
#include <hip/hip_runtime.h>
#include <math.h>

#define B_ 512
#define N_ 101
#define H_ 128
#define T_ 140
#define M37 0x1FFFFFFFFFull

// lgkm-only barrier: does NOT drain vmcnt (global prefetches stay in flight)
#define BAR() asm volatile("s_waitcnt lgkmcnt(0)\n\ts_barrier" ::: "memory")
#define LGKM0() asm volatile("s_waitcnt lgkmcnt(0)" ::: "memory")

// ---------------- DPP wave64 reductions ----------------
template <int CTRL, int RM>
__device__ __forceinline__ float dpp_max_step(float x) {
  int t = __builtin_amdgcn_update_dpp((int)0xFF800000, __float_as_int(x), CTRL, RM, 0xF, false);
  return fmaxf(x, __int_as_float(t));
}
template <int CTRL, int RM>
__device__ __forceinline__ float dpp_add_step(float x) {
  int t = __builtin_amdgcn_update_dpp(0, __float_as_int(x), CTRL, RM, 0xF, false);
  return x + __int_as_float(t);
}
__device__ __forceinline__ float wave_max64(float x) {
  x = dpp_max_step<0x111, 0xF>(x);
  x = dpp_max_step<0x112, 0xF>(x);
  x = dpp_max_step<0x114, 0xF>(x);
  x = dpp_max_step<0x118, 0xF>(x);
  x = dpp_max_step<0x142, 0xA>(x);
  x = dpp_max_step<0x143, 0xC>(x);
  return __int_as_float(__builtin_amdgcn_readlane(__float_as_int(x), 63));
}
__device__ __forceinline__ float wave_sum64(float x) {
  x = dpp_add_step<0x111, 0xF>(x);
  x = dpp_add_step<0x112, 0xF>(x);
  x = dpp_add_step<0x114, 0xF>(x);
  x = dpp_add_step<0x118, 0xF>(x);
  x = dpp_add_step<0x142, 0xA>(x);
  x = dpp_add_step<0x143, 0xC>(x);
  return __int_as_float(__builtin_amdgcn_readlane(__float_as_int(x), 63));
}

// ---------------- low-latency xor-butterfly data movement ----------------
// Each helper returns x[lane ^ K]; pure data movement. HW-verified (R2/R3/R5,
// absmax 0.0). Register-neutral.
__device__ __forceinline__ float bfly_xor16(float x) {
  // ds_swizzle BitMode: and=0x1F, or=0, xor=16 -> (16<<10)|0x1F
  return __int_as_float(__builtin_amdgcn_ds_swizzle(__float_as_int(x), 0x401F));
}
__device__ __forceinline__ float bfly_xor8(float x) {
  // row_ror:8 within 16-lane rows: rotate by half the ring == xor 8.
  int xi = __float_as_int(x);
  int t = __builtin_amdgcn_update_dpp(xi, xi, 0x128, 0xF, 0xF, false);
  return __int_as_float(t);
}
__device__ __forceinline__ float bfly_xor4(float x) {
  // xor 4 via two bank-masked row shifts (VALU DPP):
  //  row_shl:4 (dst[i]=src[i+4]) on banks 0,2 (lanes 0-3, 8-11)  mask 0x5
  //  row_shr:4 (dst[i]=src[i-4]) on banks 1,3 (lanes 4-7, 12-15) mask 0xA
  int xi = __float_as_int(x);
  int t = __builtin_amdgcn_update_dpp(xi, xi, 0x104, 0xF, 0x5, false);
  t = __builtin_amdgcn_update_dpp(t, xi, 0x114, 0xF, 0xA, false);
  return __int_as_float(t);
}
__device__ __forceinline__ float bfly_xor2(float x) {
  // quad_perm [2,3,0,1] = 0x4E
  int xi = __float_as_int(x);
  int t = __builtin_amdgcn_update_dpp(xi, xi, 0x4E, 0xF, 0xF, false);
  return __int_as_float(t);
}
__device__ __forceinline__ float bfly_xor1(float x) {
  // quad_perm [1,0,3,2] = 0xB1
  int xi = __float_as_int(x);
  int t = __builtin_amdgcn_update_dpp(xi, xi, 0xB1, 0xF, 0xF, false);
  return __int_as_float(t);
}

// ---------------- 128x32 GEMM tile (global-direct; used by stage_a) --------
__device__ __forceinline__ void gemm_tile_dev(
    const float* A, const float* B, float* C, int cb, int transB, int tid)
{
  int cc = cb * 32 + (tid & 7) * 4;
  int r0 = tid >> 3;
  float4 acc0 = {0,0,0,0}, acc1 = {0,0,0,0}, acc2 = {0,0,0,0}, acc3 = {0,0,0,0};
  for (int k4 = 0; k4 < 32; ++k4) {
    const int k = k4 * 4;
    float4 a0v = *(const float4*)(A + (r0 +  0) * 128 + k);
    float4 a1v = *(const float4*)(A + (r0 + 32) * 128 + k);
    float4 a2v = *(const float4*)(A + (r0 + 64) * 128 + k);
    float4 a3v = *(const float4*)(A + (r0 + 96) * 128 + k);
    float4 b0, b1, b2, b3;
    if (!transB) {
      b0 = *(const float4*)(B + (k + 0) * 128 + cc);
      b1 = *(const float4*)(B + (k + 1) * 128 + cc);
      b2 = *(const float4*)(B + (k + 2) * 128 + cc);
      b3 = *(const float4*)(B + (k + 3) * 128 + cc);
    } else {
      float4 t0 = *(const float4*)(B + (cc + 0) * 128 + k);
      float4 t1 = *(const float4*)(B + (cc + 1) * 128 + k);
      float4 t2 = *(const float4*)(B + (cc + 2) * 128 + k);
      float4 t3 = *(const float4*)(B + (cc + 3) * 128 + k);
      b0 = make_float4(t0.x, t1.x, t2.x, t3.x);
      b1 = make_float4(t0.y, t1.y, t2.y, t3.y);
      b2 = make_float4(t0.z, t1.z, t2.z, t3.z);
      b3 = make_float4(t0.w, t1.w, t2.w, t3.w);
    }
#define GSTEP(AC, BV) \
    acc0.x += a0v.AC * BV.x; acc0.y += a0v.AC * BV.y; acc0.z += a0v.AC * BV.z; acc0.w += a0v.AC * BV.w; \
    acc1.x += a1v.AC * BV.x; acc1.y += a1v.AC * BV.y; acc1.z += a1v.AC * BV.z; acc1.w += a1v.AC * BV.w; \
    acc2.x += a2v.AC * BV.x; acc2.y += a2v.AC * BV.y; acc2.z += a2v.AC * BV.z; acc2.w += a2v.AC * BV.w; \
    acc3.x += a3v.AC * BV.x; acc3.y += a3v.AC * BV.y; acc3.z += a3v.AC * BV.z; acc3.w += a3v.AC * BV.w;
    GSTEP(x, b0)
    GSTEP(y, b1)
    GSTEP(z, b2)
    GSTEP(w, b3)
#undef GSTEP
  }
  *(float4*)(C + (r0 +  0) * 128 + cc) = acc0;
  *(float4*)(C + (r0 + 32) * 128 + cc) = acc1;
  *(float4*)(C + (r0 + 64) * 128 + cc) = acc2;
  *(float4*)(C + (r0 + 96) * 128 + cc) = acc3;
}

// n1: Wfw(4) + Wc(4) + wcap(1) + M^2(4)
__global__ __launch_bounds__(256) void stage_a(
    const float* __restrict__ Wfc, const float* __restrict__ Ww,
    const float* __restrict__ Wpk, const float* __restrict__ Wat,
    const float* __restrict__ F,
    float* __restrict__ Wfw, float* __restrict__ Wc, float* __restrict__ wcap,
    float* __restrict__ Mbuf)
{
  int j = blockIdx.x, tid = threadIdx.x;
  if (j < 4)       gemm_tile_dev(Wfc, Ww, Wfw, j, 0, tid);
  else if (j < 8)  gemm_tile_dev(Wpk, Wat, Wc, j - 4, 1, tid);
  else if (j == 8) {
    if (tid < 128) {
      float s = 0.f;
      for (int k = 0; k < 128; ++k) s += Wfc[128 * 128 + k] * Ww[k * 128 + tid];
      wcap[tid] = s;
    }
  } else gemm_tile_dev(F, F, Mbuf + 2ll * 16384, j - 9, 0, tid);
}

// stage_pipe (R10): one block = one FULL 128x128 output (all 4 cb groups).
// A tile staged once into 64 KB LDS (XOR-swizzled, R9-verified) and reused
// for 4x the FMAs (LDS:FMA 1:64 vs 1:16); global A traffic /4; 1242 blocks
// total so every launch fits one residency round. BIT-EXACT: each cb's
// accumulator chain is the textually identical expression sequence as the
// R9 1-cb block (k4 ascending, same GSTEP order, same values) - widening
// adds independent accumulators only. acc[4][4] fully unrolled (static
// indices; rule: runtime-indexed arrays spill to scratch).
__global__ __launch_bounds__(256) void stage_pipe(
    const float* __restrict__ F, const float* __restrict__ Ww,
    const float* __restrict__ pool, const float* __restrict__ enc,
    const float* __restrict__ Wfw,
    float* __restrict__ Mbuf, float* __restrict__ Abuf,
    float* __restrict__ Qpl, float* __restrict__ encW,
    int L, int nc, int a0, int na, int q0, int nq, int e0)
{
  __shared__ __align__(16) float4 sA[4096];   // 64 KB A tile, swizzled
  int bx = blockIdx.x, tid = threadIdx.x;
  int c_end = nc, a_end = nc + na, q_end = a_end + 4 * nq;
  const float *Aptr, *Bptr;
  float* Cptr;
  if (bx < c_end) {
    int s = bx + 1;
    Aptr = (s == 1) ? F : Mbuf + (long long)s * 16384;
    Bptr = Mbuf + (long long)L * 16384;
    Cptr = Mbuf + (long long)(L + s) * 16384;
  } else if (bx < a_end) {
    int t = a0 + (bx - c_end);
    Aptr = (t == 0) ? F : Mbuf + (long long)(t + 1) * 16384;
    Bptr = Ww;
    Cptr = Abuf + (long long)t * 16384;
  } else if (bx < q_end) {
    int j = bx - a_end, t = q0 + (j >> 2), rb = j & 3;
    Aptr = pool + (long long)rb * 16384;
    Bptr = Abuf + (long long)t * 16384;
    Cptr = Qpl + (long long)t * 65536 + (long long)rb * 16384;
  } else {
    int rb = e0 + (bx - q_end);
    Aptr = enc + (long long)rb * 16384;
    Bptr = Wfw;
    Cptr = encW + (long long)rb * 16384;
  }

  // stage A (128 rows x 32 float4) into LDS, swizzled (R9-verified)
  {
    const float4* A4 = (const float4*)Aptr;
    for (int i = tid; i < 4096; i += 256) {
      int row = i >> 5, c4 = i & 31;
      sA[(row << 5) + (c4 ^ (row & 7))] = A4[i];
    }
  }
  __syncthreads();

  const int cbase = (tid & 7) * 4;
  const int r0 = tid >> 3;
  const int sx = r0 & 7;        // (r0+32m)&7 == r0&7 for all four row reads
  float4 acc[4][4];
#pragma unroll
  for (int c = 0; c < 4; ++c)
#pragma unroll
    for (int m = 0; m < 4; ++m) acc[c][m] = make_float4(0.f, 0.f, 0.f, 0.f);

#define GS(C, AC, BV) \
    acc[C][0].x += a0v.AC * BV.x; acc[C][0].y += a0v.AC * BV.y; acc[C][0].z += a0v.AC * BV.z; acc[C][0].w += a0v.AC * BV.w; \
    acc[C][1].x += a1v.AC * BV.x; acc[C][1].y += a1v.AC * BV.y; acc[C][1].z += a1v.AC * BV.z; acc[C][1].w += a1v.AC * BV.w; \
    acc[C][2].x += a2v.AC * BV.x; acc[C][2].y += a2v.AC * BV.y; acc[C][2].z += a2v.AC * BV.z; acc[C][2].w += a2v.AC * BV.w; \
    acc[C][3].x += a3v.AC * BV.x; acc[C][3].y += a3v.AC * BV.y; acc[C][3].z += a3v.AC * BV.z; acc[C][3].w += a3v.AC * BV.w;

  for (int k4 = 0; k4 < 32; ++k4) {
    const int k = k4 * 4;
    const int kx = k4 ^ sx;
    float4 a0v = sA[((r0 +  0) << 5) + kx];
    float4 a1v = sA[((r0 + 32) << 5) + kx];
    float4 a2v = sA[((r0 + 64) << 5) + kx];
    float4 a3v = sA[((r0 + 96) << 5) + kx];
#pragma unroll
    for (int c = 0; c < 4; ++c) {
      const int cc = c * 32 + cbase;
      float4 b0 = *(const float4*)(Bptr + (k + 0) * 128 + cc);
      float4 b1 = *(const float4*)(Bptr + (k + 1) * 128 + cc);
      float4 b2 = *(const float4*)(Bptr + (k + 2) * 128 + cc);
      float4 b3 = *(const float4*)(Bptr + (k + 3) * 128 + cc);
      GS(c, x, b0)
      GS(c, y, b1)
      GS(c, z, b2)
      GS(c, w, b3)
    }
  }
#undef GS

#pragma unroll
  for (int c = 0; c < 4; ++c) {
    const int cc = c * 32 + cbase;
    *(float4*)(Cptr + (r0 +  0) * 128 + cc) = acc[c][0];
    *(float4*)(Cptr + (r0 + 32) * 128 + cc) = acc[c][1];
    *(float4*)(Cptr + (r0 + 64) * 128 + cc) = acc[c][2];
    *(float4*)(Cptr + (r0 + 96) * 128 + cc) = acc[c][3];
  }
}

// ---------------- fused Q-build + compat + softmax (per-wave, no block barrier)
// Verbatim R5 (passed, 683 us, absmax 0.0). R6 lessons: the s_qs LDS
// broadcast round-trip is latency-hidden and BEATS a serial readlane chain;
// FP expression trees are untouchable (R4).
__device__ __forceinline__ void compat_sm(
    int wave, int lane, int amaxU, float capU,
    unsigned long long msklo, unsigned long long mskhi,
    const float* s_buf, const float* s_wc, const float* s_qp,
    float* s_qs, const float* kreg, float* s_sc)
{
  if (lane < 32) {
    int d = (lane < 16) ? (wave * 16 + lane) : ((wave + 4) * 16 + (lane - 16));
    float qv = s_buf[amaxU * H_ + d] + capU * s_wc[d] + s_qp[d];
    s_qs[wave * 32 + lane] = qv;
  }
  LGKM0();
  const float4* q0 = (const float4*)(s_qs + wave * 32);
  const float4* q1 = (const float4*)(s_qs + wave * 32 + 16);
  float c00 = 0.f, c01 = 0.f, c10 = 0.f, c11 = 0.f;
#pragma unroll
  for (int q = 0; q < 4; ++q) {
    float4 qq = q0[q];
    c00 += qq.x * kreg[q * 4 + 0] + qq.y * kreg[q * 4 + 1]
         + qq.z * kreg[q * 4 + 2] + qq.w * kreg[q * 4 + 3];
    c10 += qq.x * kreg[32 + q * 4 + 0] + qq.y * kreg[32 + q * 4 + 1]
         + qq.z * kreg[32 + q * 4 + 2] + qq.w * kreg[32 + q * 4 + 3];
    float4 qr = q1[q];
    c01 += qr.x * kreg[16 + q * 4 + 0] + qr.y * kreg[16 + q * 4 + 1]
         + qr.z * kreg[16 + q * 4 + 2] + qr.w * kreg[16 + q * 4 + 3];
    c11 += qr.x * kreg[48 + q * 4 + 0] + qr.y * kreg[48 + q * 4 + 1]
         + qr.z * kreg[48 + q * 4 + 2] + qr.w * kreg[48 + q * 4 + 3];
  }
  bool mb0 = (msklo >> lane) & 1ull;
  bool mb1v = (lane < 37) ? ((mskhi >> lane) & 1ull) : true;
  float a0 = mb0 ? -INFINITY : 0.25f * c00;
  float a1 = mb0 ? -INFINITY : 0.25f * c01;
  float b0 = mb1v ? -INFINITY : 0.25f * c10;
  float b1 = mb1v ? -INFINITY : 0.25f * c11;

  float m0  = wave_max64(fmaxf(a0, b0));
  float m1v = wave_max64(fmaxf(a1, b1));
  float ea0 = expf(a0 - m0),  eb0 = (lane < 37) ? expf(b0 - m0)  : 0.f;
  float ea1 = expf(a1 - m1v), eb1 = (lane < 37) ? expf(b1 - m1v) : 0.f;
  float s0 = ea0 + eb0, s1 = ea1 + eb1;
  // butterfly: identical add order (32,16,8,4,2,1); DPP/swizzle movement.
  { float t0 = __shfl_xor(s0, 32), t1 = __shfl_xor(s1, 32); s0 += t0; s1 += t1; }
  { float t0 = bfly_xor16(s0),     t1 = bfly_xor16(s1);     s0 += t0; s1 += t1; }
  { float t0 = bfly_xor8(s0),      t1 = bfly_xor8(s1);      s0 += t0; s1 += t1; }
  { float t0 = bfly_xor4(s0),      t1 = bfly_xor4(s1);      s0 += t0; s1 += t1; }
  { float t0 = bfly_xor2(s0),      t1 = bfly_xor2(s1);      s0 += t0; s1 += t1; }
  { float t0 = bfly_xor1(s0),      t1 = bfly_xor1(s1);      s0 += t0; s1 += t1; }
  float* r0 = s_sc + wave * 104;
  float* r1 = s_sc + (wave + 4) * 104;
  r0[lane] = ea0 / s0; r1[lane] = ea1 / s1;
  if (lane < 37) { r0[64 + lane] = eb0 / s0; r1[64 + lane] = eb1 / s1; }
}

// =====================================================================
// Decode: verbatim R5 (683 us, absmax 0.0; bit-stable across R7/R8/R9).
// R5 = R3 + bit-exact in-register glimpse half-combine via bfly_xor16.
// REGISTER-CLIFF: kreg[64]+vreg[51]+preg[64]; t-loop edits must be
// register-neutral (R2 lesson). FP trees frozen (R4 lesson).
// =====================================================================
__global__ __attribute__((amdgpu_flat_work_group_size(256, 256), amdgpu_waves_per_eu(2, 2)))
void decode_kernel(
    const float* __restrict__ enc,
    const float* __restrict__ Wk,
    const float* __restrict__ Wv,
    const float* __restrict__ Wc,
    const float* __restrict__ encW,
    const float* __restrict__ Qpool,
    const float* __restrict__ wcap,
    const float* __restrict__ capcity,
    const float* __restrict__ demand,
    float* __restrict__ out)
{
  __shared__ __align__(16) float s_buf[N_ * 132];  // enc (pad 132) -> encW (stride 128)
  __shared__ __align__(16) float s_sc[8 * 104];
  __shared__ __align__(16) float s_part[128];      // combined glimpse (R5)
  __shared__ __align__(16) float s_p2[256];
  __shared__ __align__(16) float s_qs[128];        // per-wave Q scratch (4 x 32)
  __shared__ __align__(16) float s_wc[128];
  __shared__ __align__(16) float s_qp[128];

  const int b    = blockIdx.x;
  const int tid  = threadIdx.x;
  const int lane = tid & 63;
  const int wave = tid >> 6;
  const int an = tid & 127, aj = tid >> 7;   // role A (comp2): n row, dim half
  // glimpse ownership remap: wave-local heads {wave, wave+4}
  const int bh2 = (lane >> 4) & 1;                                   // n half
  const int bj2 = (wave + ((lane >= 32) ? 4 : 0)) * 16 + (lane & 15); // out dim
  const float invSqrtH = 0.08838834764831845f;

  float cap  = capcity[b];
  float cap0 = capcity[0];
  float dem0 = demand[(long long)b * N_ + lane];
  float dem1 = (lane < 37) ? demand[(long long)b * N_ + 64 + lane] : 0.f;
  float wcr  = (tid < 128) ? wcap[tid] : 0.f;
  float qp0  = (tid < 128) ? Qpool[(long long)b * H_ + tid] : 0.f;

  // ---- stage enc[b] into LDS (pad 132) ----
  for (int idx = tid; idx < N_ * 32; idx += 256) {
    int row = idx >> 5, q = idx & 31;
    float4 v = *(const float4*)(enc + ((long long)b * N_ + row) * H_ + q * 4);
    float* d = s_buf + row * 132 + q * 4;
    d[0] = v.x; d[1] = v.y; d[2] = v.z; d[3] = v.w;
  }
  BAR();

  // ---- V column slices (remapped ownership): vreg[nl] = V[bh2*51+nl][bj2] ----
  float vreg[51];
#pragma unroll
  for (int q = 0; q < 51; ++q) vreg[q] = 0.f;
  {
    const int base = bh2 * 51;
    for (int i4 = 0; i4 < 32; ++i4) {
      float w0 = Wv[(i4 * 4 + 0) * H_ + bj2];
      float w1 = Wv[(i4 * 4 + 1) * H_ + bj2];
      float w2 = Wv[(i4 * 4 + 2) * H_ + bj2];
      float w3 = Wv[(i4 * 4 + 3) * H_ + bj2];
#pragma unroll
      for (int nl = 0; nl < 51; ++nl) {
        if (base + nl < N_) {
          float4 e = *(const float4*)(s_buf + (base + nl) * 132 + i4 * 4);
          vreg[nl] += e.x * w0 + e.y * w1 + e.z * w2 + e.w * w3;
        }
      }
    }
  }

  // ---- K rows, per-wave layout ----
  float kreg[64];
#pragma unroll
  for (int q = 0; q < 64; ++q) kreg[q] = 0.f;
  {
    const int n0 = lane;
    const int n1c = (lane < 37) ? 64 + lane : 0;
    for (int i = 0; i < 128; ++i) {
      float e0 = s_buf[n0 * 132 + i];
      float e1 = s_buf[n1c * 132 + i];
      const float4* wk0 = (const float4*)(Wk + i * H_ + wave * 16);
      const float4* wk1 = (const float4*)(Wk + i * H_ + (wave + 4) * 16);
#pragma unroll
      for (int q = 0; q < 4; ++q) {
        float4 a = wk0[q];
        kreg[q * 4 + 0] += e0 * a.x; kreg[q * 4 + 1] += e0 * a.y;
        kreg[q * 4 + 2] += e0 * a.z; kreg[q * 4 + 3] += e0 * a.w;
        kreg[32 + q * 4 + 0] += e1 * a.x; kreg[32 + q * 4 + 1] += e1 * a.y;
        kreg[32 + q * 4 + 2] += e1 * a.z; kreg[32 + q * 4 + 3] += e1 * a.w;
        float4 c = wk1[q];
        kreg[16 + q * 4 + 0] += e0 * c.x; kreg[16 + q * 4 + 1] += e0 * c.y;
        kreg[16 + q * 4 + 2] += e0 * c.z; kreg[16 + q * 4 + 3] += e0 * c.w;
        kreg[48 + q * 4 + 0] += e1 * c.x; kreg[48 + q * 4 + 1] += e1 * c.y;
        kreg[48 + q * 4 + 2] += e1 * c.z; kreg[48 + q * 4 + 3] += e1 * c.w;
      }
    }
  }

  // ---- P rows (role A): preg = Kp2[an][aj*64 .. +64] ----
  float preg[64];
#pragma unroll
  for (int q = 0; q < 64; ++q) preg[q] = 0.f;
  if (an < N_) {
    for (int i = 0; i < 128; ++i) {
      float e = s_buf[an * 132 + i];
      const float4* wc = (const float4*)(Wc + i * H_ + aj * 64);
#pragma unroll
      for (int q = 0; q < 16; ++q) {
        float4 c = wc[q];
        preg[q * 4 + 0] += e * c.x; preg[q * 4 + 1] += e * c.y;
        preg[q * 4 + 2] += e * c.z; preg[q * 4 + 3] += e * c.w;
      }
    }
  }
  BAR();

  // ---- overwrite s_buf with encW (stride 128); stage s_wc / s_qp ----
  for (int idx = tid; idx < N_ * 32; idx += 256) {
    int row = idx >> 5, q = idx & 31;
    float4 v = *(const float4*)(encW + ((long long)b * N_ + row) * H_ + q * 4);
    float* d = s_buf + row * 128 + q * 4;
    d[0] = v.x; d[1] = v.y; d[2] = v.z; d[3] = v.w;
  }
  if (tid < 128) { s_wc[tid] = wcr; s_qp[tid] = qp0; }
  BAR();

  // ---- initial mask + peeled step-0 compat+softmax (amax=0, cap=initial) ----
  unsigned long long m1lo = 1ull, m1hi = 0ull;
  unsigned long long msklo, mskhi;
  {
    bool p0i = (lane == 0) || (dem0 > cap);
    bool p1i = (lane < 37) ? (dem1 > cap) : true;
    msklo = __ballot(p0i);
    mskhi = __ballot(p1i) & M37;
    if (msklo == ~0ull && mskhi == M37) msklo &= ~1ull;
  }
  float logpAcc = 0.f;
  compat_sm(wave, lane, 0, cap, msklo, mskhi, s_buf, s_wc, s_qp, s_qs, kreg, s_sc);
  // no barrier: glimpse below reads only this wave's s_sc rows

  for (int t = 0; t < T_; ++t) {
    int tn = (t + 1 < T_) ? (t + 1) : t;
    float qn = (tid < 128) ? Qpool[((long long)tn * B_ + b) * H_ + tid] : 0.f;

    // ---- B: glimpse partial (wave-local heads) + in-register half-combine ----
    {
      LGKM0();  // own-wave s_sc writes from compat_sm
      const float* srow = s_sc + (bj2 >> 4) * 104;
      float acc = 0.f;
      if (bh2 == 0) {
#pragma unroll
        for (int q = 0; q < 12; ++q) {
          float4 sv = *(const float4*)(srow + q * 4);
          acc += sv.x * vreg[q * 4 + 0] + sv.y * vreg[q * 4 + 1]
               + sv.z * vreg[q * 4 + 2] + sv.w * vreg[q * 4 + 3];
        }
        acc += srow[48] * vreg[48] + srow[49] * vreg[49] + srow[50] * vreg[50];
      } else {
        acc += srow[51] * vreg[0];
#pragma unroll
        for (int q = 0; q < 12; ++q) {
          float4 sv = *(const float4*)(srow + 52 + q * 4);
          acc += sv.x * vreg[1 + q * 4] + sv.y * vreg[2 + q * 4]
               + sv.z * vreg[3 + q * 4] + sv.w * vreg[4 + q * 4];
        }
        acc += srow[100] * vreg[49];
      }
      // lane^16 holds the other n-half of the SAME bj2; for bh2==0 lanes
      // gl = half0 + half1 == R3's g0+g1 order -> bit-identical.
      float gl = acc + bfly_xor16(acc);
      if (bh2 == 0) s_part[bj2] = gl;
    }
    BAR();

    // ---- C: comp2 partial (role A, combined-glimpse reads) + s_qp refresh ----
    if (an < N_) {
      const float4* p0 = (const float4*)(s_part + aj * 64);
      float c = 0.f;
#pragma unroll
      for (int q = 0; q < 16; ++q) {
        float4 g0 = p0[q];
        c += g0.x * preg[q * 4 + 0] + g0.y * preg[q * 4 + 1]
           + g0.z * preg[q * 4 + 2] + g0.w * preg[q * 4 + 3];
      }
      s_p2[aj * 128 + an] = c;
    }
    if (tid < 128) s_qp[tid] = qn;
    BAR();

    // ---- DA: logits, argmax, lse, state, then fused next-step compat ----
    {
      float l0 = -INFINITY, l1 = -INFINITY;
      bool mb0 = (msklo >> lane) & 1ull;
      if (!mb0) l0 = 10.f * tanhf((s_p2[lane] + s_p2[128 + lane]) * invSqrtH);
      if (lane < 37) {
        bool mb1 = (mskhi >> lane) & 1ull;
        if (!mb1) l1 = 10.f * tanhf((s_p2[64 + lane] + s_p2[192 + lane]) * invSqrtH);
      }
      float vmax = wave_max64(fmaxf(l0, l1));
      unsigned long long blo = __ballot(l0 == vmax);
      unsigned long long bhi = __ballot(l1 == vmax);
      int amax = blo ? (__ffsll((long long)blo) - 1)
                     : (64 + __ffsll((long long)bhi) - 1);
      if (wave == 0) {
        // logp path only used by tid 0 -> waves 1-3 skip it entirely
        float ss = wave_sum64(__expf(l0 - vmax) + __expf(l1 - vmax));
        logpAcc -= __logf(ss);
      }

      float dlo = __int_as_float(__builtin_amdgcn_readlane(__float_as_int(dem0), amax & 63));
      float dhi = __int_as_float(__builtin_amdgcn_readlane(__float_as_int(dem1), amax & 63));
      float capNew = (amax == 0) ? cap0 : (cap - ((amax < 64) ? dlo : dhi));
      if (amax < 64) m1lo |= (1ull << amax); else m1hi |= (1ull << (amax - 64));
      m1lo = (m1lo & ~1ull) | (unsigned long long)(amax == 0);
      bool doneNew = ((int)__popcll(m1lo & ~1ull) + (int)__popcll(m1hi)) >= (N_ - 1);
      bool p0m = ((m1lo >> lane) & 1ull) || (dem0 > capNew);
      bool p1m = (lane < 37) ? (((m1hi >> lane) & 1ull) || (dem1 > capNew)) : true;
      unsigned long long klo = __ballot(p0m);
      unsigned long long khi = __ballot(p1m) & M37;
      if (klo == ~0ull && khi == M37) klo &= ~1ull;
      msklo = klo; mskhi = khi; cap = capNew;

      if (tid == 0) out[(long long)b * T_ + t] = (float)amax;
      if (doneNew) {
        // post-done trajectory is provably all-zeros with zero logp deltas
        for (int tt = t + 1 + tid; tt < T_; tt += 256)
          out[(long long)b * T_ + tt] = 0.f;
        break;
      }
      if (t + 1 < T_)
        compat_sm(wave, lane, amax, capNew, msklo, mskhi,
                  s_buf, s_wc, s_qp, s_qs, kreg, s_sc);
      // no barrier: next glimpse reads only this wave's s_sc rows
    }
  }

  if (tid == 0) out[(long long)B_ * T_ + b] = logpAcc;
}

// =====================================================================
extern "C" void kernel_launch(void* const* d_in, const int* in_sizes, int n_in,
                              void* d_out, int out_size, void* d_ws, size_t ws_size,
                              hipStream_t stream)
{
  const float* enc   = (const float*)d_in[0];
  const float* pool  = (const float*)d_in[1];
  const float* cap   = (const float*)d_in[3];
  const float* dem   = (const float*)d_in[4];
  const float* W_fc  = (const float*)d_in[7];   // 129x128
  const float* W_fc1 = (const float*)d_in[8];   // 128x128 (= F)
  const float* W_w   = (const float*)d_in[9];
  const float* W_kk  = (const float*)d_in[10];
  const float* W_vv  = (const float*)d_in[11];
  const float* W_at  = (const float*)d_in[12];
  const float* W_pk  = (const float*)d_in[13];
  float* out = (float*)d_out;
  float* ws  = (float*)d_ws;

  float* Mbuf  = ws;                               // 141 * 16384 (slots 2..140 used)
  float* Abuf  = Mbuf + 141 * 16384;               // 140 * 16384
  float* Qpl   = Abuf + 140 * 16384;               // 140 * 512 * 128
  float* encW  = Qpl + 140 * 512 * 128;            // 512 * 101 * 128
  float* Wfw   = encW + 512 * 101 * 128;           // 16384
  float* Wc    = Wfw + 16384;                      // 16384
  float* wcapb = Wc + 16384;                       // 128

  stage_a<<<13, 256, 0, stream>>>(W_fc, W_w, W_pk, W_at, W_fc1, Wfw, Wc, wcapb, Mbuf);

  // Pipelined packed stages (R8 schedule, grids /4 for full-output blocks):
  // one block = one 128x128 output. Deps: A_t needs M^{t+1} (prev launch);
  // Qp_t needs A_t (prev launch); encW needs Wfw (stage_a).
  // grid = nc + na + 4*nq + (#encW outputs).
  stage_pipe<<<128, 256, 0, stream>>>(W_fc1, W_w, pool, enc, Wfw, Mbuf, Abuf, Qpl, encW,
                                      2, 2,   0, 0,   0, 0,   0);     // 2 chain + 126 encW
  stage_pipe<<<128, 256, 0, stream>>>(W_fc1, W_w, pool, enc, Wfw, Mbuf, Abuf, Qpl, encW,
                                      4, 4,   0, 4,   0, 0,   126);   // 4 + 4 + 120 encW
  stage_pipe<<<128, 256, 0, stream>>>(W_fc1, W_w, pool, enc, Wfw, Mbuf, Abuf, Qpl, encW,
                                      8, 8,   4, 4,   0, 4,   246);   // 8 + 4 + 16 + 100 encW
  stage_pipe<<<98, 256, 0, stream>>>(W_fc1, W_w, pool, enc, Wfw, Mbuf, Abuf, Qpl, encW,
                                      16, 16, 8, 8,   4, 4,   346);   // 16 + 8 + 16 + 58 encW
  stage_pipe<<<80, 256, 0, stream>>>(W_fc1, W_w, pool, enc, Wfw, Mbuf, Abuf, Qpl, encW,
                                      32, 32, 16, 16, 8, 8,   0);     // 32 + 16 + 32
  stage_pipe<<<160, 256, 0, stream>>>(W_fc1, W_w, pool, enc, Wfw, Mbuf, Abuf, Qpl, encW,
                                      64, 64, 32, 32, 16, 16, 0);     // 64 + 32 + 64
  stage_pipe<<<204, 256, 0, stream>>>(W_fc1, W_w, pool, enc, Wfw, Mbuf, Abuf, Qpl, encW,
                                      128, 12, 64, 64, 32, 32, 0);    // 12 + 64 + 128
  stage_pipe<<<268, 256, 0, stream>>>(W_fc1, W_w, pool, enc, Wfw, Mbuf, Abuf, Qpl, encW,
                                      0, 0,   128, 12, 64, 64, 0);    // 12 + 256
  stage_pipe<<<48, 256, 0, stream>>>(W_fc1, W_w, pool, enc, Wfw, Mbuf, Abuf, Qpl, encW,
                                      0, 0,   0, 0,   128, 12, 0);    // 48

  decode_kernel<<<512, 256, 0, stream>>>(enc, W_kk, W_vv, Wc, encW, Qpl, wcapb, cap, dem, out);
}

// Round 12
// 888.912 us; speedup vs baseline: 1.1330x; 1.1330x over previous
//
#include <hip/hip_runtime.h>
#include <math.h>

#define B_ 512
#define N_ 101
#define H_ 128
#define T_ 140
#define M37 0x1FFFFFFFFFull

// lgkm-only barrier: does NOT drain vmcnt (global prefetches stay in flight)
#define BAR() asm volatile("s_waitcnt lgkmcnt(0)\n\ts_barrier" ::: "memory")
#define LGKM0() asm volatile("s_waitcnt lgkmcnt(0)" ::: "memory")

// ---------------- DPP wave64 reductions ----------------
template <int CTRL, int RM>
__device__ __forceinline__ float dpp_max_step(float x) {
  int t = __builtin_amdgcn_update_dpp((int)0xFF800000, __float_as_int(x), CTRL, RM, 0xF, false);
  return fmaxf(x, __int_as_float(t));
}
template <int CTRL, int RM>
__device__ __forceinline__ float dpp_add_step(float x) {
  int t = __builtin_amdgcn_update_dpp(0, __float_as_int(x), CTRL, RM, 0xF, false);
  return x + __int_as_float(t);
}
__device__ __forceinline__ float wave_max64(float x) {
  x = dpp_max_step<0x111, 0xF>(x);
  x = dpp_max_step<0x112, 0xF>(x);
  x = dpp_max_step<0x114, 0xF>(x);
  x = dpp_max_step<0x118, 0xF>(x);
  x = dpp_max_step<0x142, 0xA>(x);
  x = dpp_max_step<0x143, 0xC>(x);
  return __int_as_float(__builtin_amdgcn_readlane(__float_as_int(x), 63));
}
__device__ __forceinline__ float wave_sum64(float x) {
  x = dpp_add_step<0x111, 0xF>(x);
  x = dpp_add_step<0x112, 0xF>(x);
  x = dpp_add_step<0x114, 0xF>(x);
  x = dpp_add_step<0x118, 0xF>(x);
  x = dpp_add_step<0x142, 0xA>(x);
  x = dpp_add_step<0x143, 0xC>(x);
  return __int_as_float(__builtin_amdgcn_readlane(__float_as_int(x), 63));
}

// ---------------- low-latency xor-butterfly data movement ----------------
// Each helper returns x[lane ^ K]; pure data movement. HW-verified (R2/R3/R5,
// absmax 0.0). Register-neutral.
__device__ __forceinline__ float bfly_xor16(float x) {
  // ds_swizzle BitMode: and=0x1F, or=0, xor=16 -> (16<<10)|0x1F
  return __int_as_float(__builtin_amdgcn_ds_swizzle(__float_as_int(x), 0x401F));
}
__device__ __forceinline__ float bfly_xor8(float x) {
  // row_ror:8 within 16-lane rows: rotate by half the ring == xor 8.
  int xi = __float_as_int(x);
  int t = __builtin_amdgcn_update_dpp(xi, xi, 0x128, 0xF, 0xF, false);
  return __int_as_float(t);
}
__device__ __forceinline__ float bfly_xor4(float x) {
  // xor 4 via two bank-masked row shifts (VALU DPP):
  //  row_shl:4 (dst[i]=src[i+4]) on banks 0,2 (lanes 0-3, 8-11)  mask 0x5
  //  row_shr:4 (dst[i]=src[i-4]) on banks 1,3 (lanes 4-7, 12-15) mask 0xA
  int xi = __float_as_int(x);
  int t = __builtin_amdgcn_update_dpp(xi, xi, 0x104, 0xF, 0x5, false);
  t = __builtin_amdgcn_update_dpp(t, xi, 0x114, 0xF, 0xA, false);
  return __int_as_float(t);
}
__device__ __forceinline__ float bfly_xor2(float x) {
  // quad_perm [2,3,0,1] = 0x4E
  int xi = __float_as_int(x);
  int t = __builtin_amdgcn_update_dpp(xi, xi, 0x4E, 0xF, 0xF, false);
  return __int_as_float(t);
}
__device__ __forceinline__ float bfly_xor1(float x) {
  // quad_perm [1,0,3,2] = 0xB1
  int xi = __float_as_int(x);
  int t = __builtin_amdgcn_update_dpp(xi, xi, 0xB1, 0xF, 0xF, false);
  return __int_as_float(t);
}

// ---------------- 128x32 GEMM tile (global-direct; used by stage_a) --------
__device__ __forceinline__ void gemm_tile_dev(
    const float* A, const float* B, float* C, int cb, int transB, int tid)
{
  int cc = cb * 32 + (tid & 7) * 4;
  int r0 = tid >> 3;
  float4 acc0 = {0,0,0,0}, acc1 = {0,0,0,0}, acc2 = {0,0,0,0}, acc3 = {0,0,0,0};
  for (int k4 = 0; k4 < 32; ++k4) {
    const int k = k4 * 4;
    float4 a0v = *(const float4*)(A + (r0 +  0) * 128 + k);
    float4 a1v = *(const float4*)(A + (r0 + 32) * 128 + k);
    float4 a2v = *(const float4*)(A + (r0 + 64) * 128 + k);
    float4 a3v = *(const float4*)(A + (r0 + 96) * 128 + k);
    float4 b0, b1, b2, b3;
    if (!transB) {
      b0 = *(const float4*)(B + (k + 0) * 128 + cc);
      b1 = *(const float4*)(B + (k + 1) * 128 + cc);
      b2 = *(const float4*)(B + (k + 2) * 128 + cc);
      b3 = *(const float4*)(B + (k + 3) * 128 + cc);
    } else {
      float4 t0 = *(const float4*)(B + (cc + 0) * 128 + k);
      float4 t1 = *(const float4*)(B + (cc + 1) * 128 + k);
      float4 t2 = *(const float4*)(B + (cc + 2) * 128 + k);
      float4 t3 = *(const float4*)(B + (cc + 3) * 128 + k);
      b0 = make_float4(t0.x, t1.x, t2.x, t3.x);
      b1 = make_float4(t0.y, t1.y, t2.y, t3.y);
      b2 = make_float4(t0.z, t1.z, t2.z, t3.z);
      b3 = make_float4(t0.w, t1.w, t2.w, t3.w);
    }
#define GSTEP(AC, BV) \
    acc0.x += a0v.AC * BV.x; acc0.y += a0v.AC * BV.y; acc0.z += a0v.AC * BV.z; acc0.w += a0v.AC * BV.w; \
    acc1.x += a1v.AC * BV.x; acc1.y += a1v.AC * BV.y; acc1.z += a1v.AC * BV.z; acc1.w += a1v.AC * BV.w; \
    acc2.x += a2v.AC * BV.x; acc2.y += a2v.AC * BV.y; acc2.z += a2v.AC * BV.z; acc2.w += a2v.AC * BV.w; \
    acc3.x += a3v.AC * BV.x; acc3.y += a3v.AC * BV.y; acc3.z += a3v.AC * BV.z; acc3.w += a3v.AC * BV.w;
    GSTEP(x, b0)
    GSTEP(y, b1)
    GSTEP(z, b2)
    GSTEP(w, b3)
#undef GSTEP
  }
  *(float4*)(C + (r0 +  0) * 128 + cc) = acc0;
  *(float4*)(C + (r0 + 32) * 128 + cc) = acc1;
  *(float4*)(C + (r0 + 64) * 128 + cc) = acc2;
  *(float4*)(C + (r0 + 96) * 128 + cc) = acc3;
}

// n1: Wfw(4) + Wc(4) + wcap(1) + M^2(4)
__global__ __launch_bounds__(256) void stage_a(
    const float* __restrict__ Wfc, const float* __restrict__ Ww,
    const float* __restrict__ Wpk, const float* __restrict__ Wat,
    const float* __restrict__ F,
    float* __restrict__ Wfw, float* __restrict__ Wc, float* __restrict__ wcap,
    float* __restrict__ Mbuf)
{
  int j = blockIdx.x, tid = threadIdx.x;
  if (j < 4)       gemm_tile_dev(Wfc, Ww, Wfw, j, 0, tid);
  else if (j < 8)  gemm_tile_dev(Wpk, Wat, Wc, j - 4, 1, tid);
  else if (j == 8) {
    if (tid < 128) {
      float s = 0.f;
      for (int k = 0; k < 128; ++k) s += Wfc[128 * 128 + k] * Ww[k * 128 + tid];
      wcap[tid] = s;
    }
  } else gemm_tile_dev(F, F, Mbuf + 2ll * 16384, j - 9, 0, tid);
}

// stage_pipe (R12): R9's 1-cb blocks + R8 launch schedule (best verified),
// but A staged in TWO 32KB column halves -> LDS 32KB -> 5 blocks/CU
// (20 waves/CU vs R9's 8) for 2.5x more B-load latency hiding.
// BIT-EXACT: k4 runs 0..31 in order with the same accumulator chain and
// same values; staging only copies. Swizzle within 16-col half:
// sA[(row<<4) + (c4 ^ (row&7))] -- per instruction 8 unique rows give 8
// distinct bank-quads (4*(k4^(row&7)) mod 32) -> all 32 banks, no conflict.
__global__ __launch_bounds__(256) void stage_pipe(
    const float* __restrict__ F, const float* __restrict__ Ww,
    const float* __restrict__ pool, const float* __restrict__ enc,
    const float* __restrict__ Wfw,
    float* __restrict__ Mbuf, float* __restrict__ Abuf,
    float* __restrict__ Qpl, float* __restrict__ encW,
    int L, int nc, int a0, int na, int q0, int nq, int e0)
{
  __shared__ __align__(16) float4 sA[2048];   // 32 KB half A tile, swizzled
  int bx = blockIdx.x, tid = threadIdx.x;
  int c_end = 4 * nc, a_end = c_end + 4 * na, q_end = a_end + 16 * nq;
  const float *Aptr, *Bptr;
  float* Cptr;
  int cb;
  if (bx < c_end) {
    int s = (bx >> 2) + 1; cb = bx & 3;
    Aptr = (s == 1) ? F : Mbuf + (long long)s * 16384;
    Bptr = Mbuf + (long long)L * 16384;
    Cptr = Mbuf + (long long)(L + s) * 16384;
  } else if (bx < a_end) {
    int j = bx - c_end, t = a0 + (j >> 2); cb = j & 3;
    Aptr = (t == 0) ? F : Mbuf + (long long)(t + 1) * 16384;
    Bptr = Ww;
    Cptr = Abuf + (long long)t * 16384;
  } else if (bx < q_end) {
    int j = bx - a_end, t = q0 + (j >> 4), sub = j & 15, rb = sub >> 2; cb = sub & 3;
    Aptr = pool + (long long)rb * 16384;
    Bptr = Abuf + (long long)t * 16384;
    Cptr = Qpl + (long long)t * 65536 + (long long)rb * 16384;
  } else {
    int j = e0 + (bx - q_end), rb = j >> 2; cb = j & 3;
    Aptr = enc + (long long)rb * 16384;
    Bptr = Wfw;
    Cptr = encW + (long long)rb * 16384;
  }

  const float4* A4 = (const float4*)Aptr;
  const int cc = cb * 32 + (tid & 7) * 4;
  const int r0 = tid >> 3;
  const int sx = r0 & 7;        // (r0+32m)&7 == r0&7 for all four row reads
  float4 acc0 = {0,0,0,0}, acc1 = {0,0,0,0}, acc2 = {0,0,0,0}, acc3 = {0,0,0,0};

#define GSTEP(AC, BV) \
    acc0.x += a0v.AC * BV.x; acc0.y += a0v.AC * BV.y; acc0.z += a0v.AC * BV.z; acc0.w += a0v.AC * BV.w; \
    acc1.x += a1v.AC * BV.x; acc1.y += a1v.AC * BV.y; acc1.z += a1v.AC * BV.z; acc1.w += a1v.AC * BV.w; \
    acc2.x += a2v.AC * BV.x; acc2.y += a2v.AC * BV.y; acc2.z += a2v.AC * BV.z; acc2.w += a2v.AC * BV.w; \
    acc3.x += a3v.AC * BV.x; acc3.y += a3v.AC * BV.y; acc3.z += a3v.AC * BV.z; acc3.w += a3v.AC * BV.w;

  // ---- half 0: stage A cols 0..15, compute k4 = 0..15 ----
  for (int i = tid; i < 2048; i += 256) {
    int row = i >> 4, c4 = i & 15;
    sA[(row << 4) + (c4 ^ (row & 7))] = A4[(row << 5) + c4];
  }
  __syncthreads();
  for (int k4 = 0; k4 < 16; ++k4) {
    const int k = k4 * 4;
    const int kx = k4 ^ sx;
    float4 a0v = sA[((r0 +  0) << 4) + kx];
    float4 a1v = sA[((r0 + 32) << 4) + kx];
    float4 a2v = sA[((r0 + 64) << 4) + kx];
    float4 a3v = sA[((r0 + 96) << 4) + kx];
    float4 b0 = *(const float4*)(Bptr + (k + 0) * 128 + cc);
    float4 b1 = *(const float4*)(Bptr + (k + 1) * 128 + cc);
    float4 b2 = *(const float4*)(Bptr + (k + 2) * 128 + cc);
    float4 b3 = *(const float4*)(Bptr + (k + 3) * 128 + cc);
    GSTEP(x, b0)
    GSTEP(y, b1)
    GSTEP(z, b2)
    GSTEP(w, b3)
  }
  __syncthreads();

  // ---- half 1: stage A cols 16..31, compute k4 = 16..31 ----
  for (int i = tid; i < 2048; i += 256) {
    int row = i >> 4, c4 = i & 15;
    sA[(row << 4) + (c4 ^ (row & 7))] = A4[(row << 5) + 16 + c4];
  }
  __syncthreads();
  for (int k4 = 16; k4 < 32; ++k4) {
    const int k = k4 * 4;
    const int kx = (k4 - 16) ^ sx;
    float4 a0v = sA[((r0 +  0) << 4) + kx];
    float4 a1v = sA[((r0 + 32) << 4) + kx];
    float4 a2v = sA[((r0 + 64) << 4) + kx];
    float4 a3v = sA[((r0 + 96) << 4) + kx];
    float4 b0 = *(const float4*)(Bptr + (k + 0) * 128 + cc);
    float4 b1 = *(const float4*)(Bptr + (k + 1) * 128 + cc);
    float4 b2 = *(const float4*)(Bptr + (k + 2) * 128 + cc);
    float4 b3 = *(const float4*)(Bptr + (k + 3) * 128 + cc);
    GSTEP(x, b0)
    GSTEP(y, b1)
    GSTEP(z, b2)
    GSTEP(w, b3)
  }
#undef GSTEP

  *(float4*)(Cptr + (r0 +  0) * 128 + cc) = acc0;
  *(float4*)(Cptr + (r0 + 32) * 128 + cc) = acc1;
  *(float4*)(Cptr + (r0 + 64) * 128 + cc) = acc2;
  *(float4*)(Cptr + (r0 + 96) * 128 + cc) = acc3;
}

// ---------------- fused Q-build + compat + softmax (per-wave, no block barrier)
// Verbatim R5 (passed, 683 us, absmax 0.0). R6 lessons: the s_qs LDS
// broadcast round-trip is latency-hidden and BEATS a serial readlane chain;
// FP expression trees are untouchable (R4).
__device__ __forceinline__ void compat_sm(
    int wave, int lane, int amaxU, float capU,
    unsigned long long msklo, unsigned long long mskhi,
    const float* s_buf, const float* s_wc, const float* s_qp,
    float* s_qs, const float* kreg, float* s_sc)
{
  if (lane < 32) {
    int d = (lane < 16) ? (wave * 16 + lane) : ((wave + 4) * 16 + (lane - 16));
    float qv = s_buf[amaxU * H_ + d] + capU * s_wc[d] + s_qp[d];
    s_qs[wave * 32 + lane] = qv;
  }
  LGKM0();
  const float4* q0 = (const float4*)(s_qs + wave * 32);
  const float4* q1 = (const float4*)(s_qs + wave * 32 + 16);
  float c00 = 0.f, c01 = 0.f, c10 = 0.f, c11 = 0.f;
#pragma unroll
  for (int q = 0; q < 4; ++q) {
    float4 qq = q0[q];
    c00 += qq.x * kreg[q * 4 + 0] + qq.y * kreg[q * 4 + 1]
         + qq.z * kreg[q * 4 + 2] + qq.w * kreg[q * 4 + 3];
    c10 += qq.x * kreg[32 + q * 4 + 0] + qq.y * kreg[32 + q * 4 + 1]
         + qq.z * kreg[32 + q * 4 + 2] + qq.w * kreg[32 + q * 4 + 3];
    float4 qr = q1[q];
    c01 += qr.x * kreg[16 + q * 4 + 0] + qr.y * kreg[16 + q * 4 + 1]
         + qr.z * kreg[16 + q * 4 + 2] + qr.w * kreg[16 + q * 4 + 3];
    c11 += qr.x * kreg[48 + q * 4 + 0] + qr.y * kreg[48 + q * 4 + 1]
         + qr.z * kreg[48 + q * 4 + 2] + qr.w * kreg[48 + q * 4 + 3];
  }
  bool mb0 = (msklo >> lane) & 1ull;
  bool mb1v = (lane < 37) ? ((mskhi >> lane) & 1ull) : true;
  float a0 = mb0 ? -INFINITY : 0.25f * c00;
  float a1 = mb0 ? -INFINITY : 0.25f * c01;
  float b0 = mb1v ? -INFINITY : 0.25f * c10;
  float b1 = mb1v ? -INFINITY : 0.25f * c11;

  float m0  = wave_max64(fmaxf(a0, b0));
  float m1v = wave_max64(fmaxf(a1, b1));
  float ea0 = expf(a0 - m0),  eb0 = (lane < 37) ? expf(b0 - m0)  : 0.f;
  float ea1 = expf(a1 - m1v), eb1 = (lane < 37) ? expf(b1 - m1v) : 0.f;
  float s0 = ea0 + eb0, s1 = ea1 + eb1;
  // butterfly: identical add order (32,16,8,4,2,1); DPP/swizzle movement.
  { float t0 = __shfl_xor(s0, 32), t1 = __shfl_xor(s1, 32); s0 += t0; s1 += t1; }
  { float t0 = bfly_xor16(s0),     t1 = bfly_xor16(s1);     s0 += t0; s1 += t1; }
  { float t0 = bfly_xor8(s0),      t1 = bfly_xor8(s1);      s0 += t0; s1 += t1; }
  { float t0 = bfly_xor4(s0),      t1 = bfly_xor4(s1);      s0 += t0; s1 += t1; }
  { float t0 = bfly_xor2(s0),      t1 = bfly_xor2(s1);      s0 += t0; s1 += t1; }
  { float t0 = bfly_xor1(s0),      t1 = bfly_xor1(s1);      s0 += t0; s1 += t1; }
  float* r0 = s_sc + wave * 104;
  float* r1 = s_sc + (wave + 4) * 104;
  r0[lane] = ea0 / s0; r1[lane] = ea1 / s1;
  if (lane < 37) { r0[64 + lane] = eb0 / s0; r1[64 + lane] = eb1 / s1; }
}

// =====================================================================
// Decode: verbatim R5 (683 us, absmax 0.0; bit-stable across R7-R11).
// R5 = R3 + bit-exact in-register glimpse half-combine via bfly_xor16.
// REGISTER-CLIFF: kreg[64]+vreg[51]+preg[64]; t-loop edits must be
// register-neutral (R2 lesson). FP trees frozen (R4 lesson).
// =====================================================================
__global__ __attribute__((amdgpu_flat_work_group_size(256, 256), amdgpu_waves_per_eu(2, 2)))
void decode_kernel(
    const float* __restrict__ enc,
    const float* __restrict__ Wk,
    const float* __restrict__ Wv,
    const float* __restrict__ Wc,
    const float* __restrict__ encW,
    const float* __restrict__ Qpool,
    const float* __restrict__ wcap,
    const float* __restrict__ capcity,
    const float* __restrict__ demand,
    float* __restrict__ out)
{
  __shared__ __align__(16) float s_buf[N_ * 132];  // enc (pad 132) -> encW (stride 128)
  __shared__ __align__(16) float s_sc[8 * 104];
  __shared__ __align__(16) float s_part[128];      // combined glimpse (R5)
  __shared__ __align__(16) float s_p2[256];
  __shared__ __align__(16) float s_qs[128];        // per-wave Q scratch (4 x 32)
  __shared__ __align__(16) float s_wc[128];
  __shared__ __align__(16) float s_qp[128];

  const int b    = blockIdx.x;
  const int tid  = threadIdx.x;
  const int lane = tid & 63;
  const int wave = tid >> 6;
  const int an = tid & 127, aj = tid >> 7;   // role A (comp2): n row, dim half
  // glimpse ownership remap: wave-local heads {wave, wave+4}
  const int bh2 = (lane >> 4) & 1;                                   // n half
  const int bj2 = (wave + ((lane >= 32) ? 4 : 0)) * 16 + (lane & 15); // out dim
  const float invSqrtH = 0.08838834764831845f;

  float cap  = capcity[b];
  float cap0 = capcity[0];
  float dem0 = demand[(long long)b * N_ + lane];
  float dem1 = (lane < 37) ? demand[(long long)b * N_ + 64 + lane] : 0.f;
  float wcr  = (tid < 128) ? wcap[tid] : 0.f;
  float qp0  = (tid < 128) ? Qpool[(long long)b * H_ + tid] : 0.f;

  // ---- stage enc[b] into LDS (pad 132) ----
  for (int idx = tid; idx < N_ * 32; idx += 256) {
    int row = idx >> 5, q = idx & 31;
    float4 v = *(const float4*)(enc + ((long long)b * N_ + row) * H_ + q * 4);
    float* d = s_buf + row * 132 + q * 4;
    d[0] = v.x; d[1] = v.y; d[2] = v.z; d[3] = v.w;
  }
  BAR();

  // ---- V column slices (remapped ownership): vreg[nl] = V[bh2*51+nl][bj2] ----
  float vreg[51];
#pragma unroll
  for (int q = 0; q < 51; ++q) vreg[q] = 0.f;
  {
    const int base = bh2 * 51;
    for (int i4 = 0; i4 < 32; ++i4) {
      float w0 = Wv[(i4 * 4 + 0) * H_ + bj2];
      float w1 = Wv[(i4 * 4 + 1) * H_ + bj2];
      float w2 = Wv[(i4 * 4 + 2) * H_ + bj2];
      float w3 = Wv[(i4 * 4 + 3) * H_ + bj2];
#pragma unroll
      for (int nl = 0; nl < 51; ++nl) {
        if (base + nl < N_) {
          float4 e = *(const float4*)(s_buf + (base + nl) * 132 + i4 * 4);
          vreg[nl] += e.x * w0 + e.y * w1 + e.z * w2 + e.w * w3;
        }
      }
    }
  }

  // ---- K rows, per-wave layout ----
  float kreg[64];
#pragma unroll
  for (int q = 0; q < 64; ++q) kreg[q] = 0.f;
  {
    const int n0 = lane;
    const int n1c = (lane < 37) ? 64 + lane : 0;
    for (int i = 0; i < 128; ++i) {
      float e0 = s_buf[n0 * 132 + i];
      float e1 = s_buf[n1c * 132 + i];
      const float4* wk0 = (const float4*)(Wk + i * H_ + wave * 16);
      const float4* wk1 = (const float4*)(Wk + i * H_ + (wave + 4) * 16);
#pragma unroll
      for (int q = 0; q < 4; ++q) {
        float4 a = wk0[q];
        kreg[q * 4 + 0] += e0 * a.x; kreg[q * 4 + 1] += e0 * a.y;
        kreg[q * 4 + 2] += e0 * a.z; kreg[q * 4 + 3] += e0 * a.w;
        kreg[32 + q * 4 + 0] += e1 * a.x; kreg[32 + q * 4 + 1] += e1 * a.y;
        kreg[32 + q * 4 + 2] += e1 * a.z; kreg[32 + q * 4 + 3] += e1 * a.w;
        float4 c = wk1[q];
        kreg[16 + q * 4 + 0] += e0 * c.x; kreg[16 + q * 4 + 1] += e0 * c.y;
        kreg[16 + q * 4 + 2] += e0 * c.z; kreg[16 + q * 4 + 3] += e0 * c.w;
        kreg[48 + q * 4 + 0] += e1 * c.x; kreg[48 + q * 4 + 1] += e1 * c.y;
        kreg[48 + q * 4 + 2] += e1 * c.z; kreg[48 + q * 4 + 3] += e1 * c.w;
      }
    }
  }

  // ---- P rows (role A): preg = Kp2[an][aj*64 .. +64] ----
  float preg[64];
#pragma unroll
  for (int q = 0; q < 64; ++q) preg[q] = 0.f;
  if (an < N_) {
    for (int i = 0; i < 128; ++i) {
      float e = s_buf[an * 132 + i];
      const float4* wc = (const float4*)(Wc + i * H_ + aj * 64);
#pragma unroll
      for (int q = 0; q < 16; ++q) {
        float4 c = wc[q];
        preg[q * 4 + 0] += e * c.x; preg[q * 4 + 1] += e * c.y;
        preg[q * 4 + 2] += e * c.z; preg[q * 4 + 3] += e * c.w;
      }
    }
  }
  BAR();

  // ---- overwrite s_buf with encW (stride 128); stage s_wc / s_qp ----
  for (int idx = tid; idx < N_ * 32; idx += 256) {
    int row = idx >> 5, q = idx & 31;
    float4 v = *(const float4*)(encW + ((long long)b * N_ + row) * H_ + q * 4);
    float* d = s_buf + row * 128 + q * 4;
    d[0] = v.x; d[1] = v.y; d[2] = v.z; d[3] = v.w;
  }
  if (tid < 128) { s_wc[tid] = wcr; s_qp[tid] = qp0; }
  BAR();

  // ---- initial mask + peeled step-0 compat+softmax (amax=0, cap=initial) ----
  unsigned long long m1lo = 1ull, m1hi = 0ull;
  unsigned long long msklo, mskhi;
  {
    bool p0i = (lane == 0) || (dem0 > cap);
    bool p1i = (lane < 37) ? (dem1 > cap) : true;
    msklo = __ballot(p0i);
    mskhi = __ballot(p1i) & M37;
    if (msklo == ~0ull && mskhi == M37) msklo &= ~1ull;
  }
  float logpAcc = 0.f;
  compat_sm(wave, lane, 0, cap, msklo, mskhi, s_buf, s_wc, s_qp, s_qs, kreg, s_sc);
  // no barrier: glimpse below reads only this wave's s_sc rows

  for (int t = 0; t < T_; ++t) {
    int tn = (t + 1 < T_) ? (t + 1) : t;
    float qn = (tid < 128) ? Qpool[((long long)tn * B_ + b) * H_ + tid] : 0.f;

    // ---- B: glimpse partial (wave-local heads) + in-register half-combine ----
    {
      LGKM0();  // own-wave s_sc writes from compat_sm
      const float* srow = s_sc + (bj2 >> 4) * 104;
      float acc = 0.f;
      if (bh2 == 0) {
#pragma unroll
        for (int q = 0; q < 12; ++q) {
          float4 sv = *(const float4*)(srow + q * 4);
          acc += sv.x * vreg[q * 4 + 0] + sv.y * vreg[q * 4 + 1]
               + sv.z * vreg[q * 4 + 2] + sv.w * vreg[q * 4 + 3];
        }
        acc += srow[48] * vreg[48] + srow[49] * vreg[49] + srow[50] * vreg[50];
      } else {
        acc += srow[51] * vreg[0];
#pragma unroll
        for (int q = 0; q < 12; ++q) {
          float4 sv = *(const float4*)(srow + 52 + q * 4);
          acc += sv.x * vreg[1 + q * 4] + sv.y * vreg[2 + q * 4]
               + sv.z * vreg[3 + q * 4] + sv.w * vreg[4 + q * 4];
        }
        acc += srow[100] * vreg[49];
      }
      // lane^16 holds the other n-half of the SAME bj2; for bh2==0 lanes
      // gl = half0 + half1 == R3's g0+g1 order -> bit-identical.
      float gl = acc + bfly_xor16(acc);
      if (bh2 == 0) s_part[bj2] = gl;
    }
    BAR();

    // ---- C: comp2 partial (role A, combined-glimpse reads) + s_qp refresh ----
    if (an < N_) {
      const float4* p0 = (const float4*)(s_part + aj * 64);
      float c = 0.f;
#pragma unroll
      for (int q = 0; q < 16; ++q) {
        float4 g0 = p0[q];
        c += g0.x * preg[q * 4 + 0] + g0.y * preg[q * 4 + 1]
           + g0.z * preg[q * 4 + 2] + g0.w * preg[q * 4 + 3];
      }
      s_p2[aj * 128 + an] = c;
    }
    if (tid < 128) s_qp[tid] = qn;
    BAR();

    // ---- DA: logits, argmax, lse, state, then fused next-step compat ----
    {
      float l0 = -INFINITY, l1 = -INFINITY;
      bool mb0 = (msklo >> lane) & 1ull;
      if (!mb0) l0 = 10.f * tanhf((s_p2[lane] + s_p2[128 + lane]) * invSqrtH);
      if (lane < 37) {
        bool mb1 = (mskhi >> lane) & 1ull;
        if (!mb1) l1 = 10.f * tanhf((s_p2[64 + lane] + s_p2[192 + lane]) * invSqrtH);
      }
      float vmax = wave_max64(fmaxf(l0, l1));
      unsigned long long blo = __ballot(l0 == vmax);
      unsigned long long bhi = __ballot(l1 == vmax);
      int amax = blo ? (__ffsll((long long)blo) - 1)
                     : (64 + __ffsll((long long)bhi) - 1);
      if (wave == 0) {
        // logp path only used by tid 0 -> waves 1-3 skip it entirely
        float ss = wave_sum64(__expf(l0 - vmax) + __expf(l1 - vmax));
        logpAcc -= __logf(ss);
      }

      float dlo = __int_as_float(__builtin_amdgcn_readlane(__float_as_int(dem0), amax & 63));
      float dhi = __int_as_float(__builtin_amdgcn_readlane(__float_as_int(dem1), amax & 63));
      float capNew = (amax == 0) ? cap0 : (cap - ((amax < 64) ? dlo : dhi));
      if (amax < 64) m1lo |= (1ull << amax); else m1hi |= (1ull << (amax - 64));
      m1lo = (m1lo & ~1ull) | (unsigned long long)(amax == 0);
      bool doneNew = ((int)__popcll(m1lo & ~1ull) + (int)__popcll(m1hi)) >= (N_ - 1);
      bool p0m = ((m1lo >> lane) & 1ull) || (dem0 > capNew);
      bool p1m = (lane < 37) ? (((m1hi >> lane) & 1ull) || (dem1 > capNew)) : true;
      unsigned long long klo = __ballot(p0m);
      unsigned long long khi = __ballot(p1m) & M37;
      if (klo == ~0ull && khi == M37) klo &= ~1ull;
      msklo = klo; mskhi = khi; cap = capNew;

      if (tid == 0) out[(long long)b * T_ + t] = (float)amax;
      if (doneNew) {
        // post-done trajectory is provably all-zeros with zero logp deltas
        for (int tt = t + 1 + tid; tt < T_; tt += 256)
          out[(long long)b * T_ + tt] = 0.f;
        break;
      }
      if (t + 1 < T_)
        compat_sm(wave, lane, amax, capNew, msklo, mskhi,
                  s_buf, s_wc, s_qp, s_qs, kreg, s_sc);
      // no barrier: next glimpse reads only this wave's s_sc rows
    }
  }

  if (tid == 0) out[(long long)B_ * T_ + b] = logpAcc;
}

// =====================================================================
extern "C" void kernel_launch(void* const* d_in, const int* in_sizes, int n_in,
                              void* d_out, int out_size, void* d_ws, size_t ws_size,
                              hipStream_t stream)
{
  const float* enc   = (const float*)d_in[0];
  const float* pool  = (const float*)d_in[1];
  const float* cap   = (const float*)d_in[3];
  const float* dem   = (const float*)d_in[4];
  const float* W_fc  = (const float*)d_in[7];   // 129x128
  const float* W_fc1 = (const float*)d_in[8];   // 128x128 (= F)
  const float* W_w   = (const float*)d_in[9];
  const float* W_kk  = (const float*)d_in[10];
  const float* W_vv  = (const float*)d_in[11];
  const float* W_at  = (const float*)d_in[12];
  const float* W_pk  = (const float*)d_in[13];
  float* out = (float*)d_out;
  float* ws  = (float*)d_ws;

  float* Mbuf  = ws;                               // 141 * 16384 (slots 2..140 used)
  float* Abuf  = Mbuf + 141 * 16384;               // 140 * 16384
  float* Qpl   = Abuf + 140 * 16384;               // 140 * 512 * 128
  float* encW  = Qpl + 140 * 512 * 128;            // 512 * 101 * 128
  float* Wfw   = encW + 512 * 101 * 128;           // 16384
  float* Wc    = Wfw + 16384;                      // 16384
  float* wcapb = Wc + 16384;                       // 128

  stage_a<<<13, 256, 0, stream>>>(W_fc, W_w, W_pk, W_at, W_fc1, Wfw, Wc, wcapb, Mbuf);

  // Pipelined packed stages (R8/R9 schedule, 4-granular): chain level rides
  // with A_t / Qp_t / encW bulk.  Deps: A_t needs M^{t+1} (prev launch);
  // Qp_t needs A_t (prev launch); encW needs Wfw (stage_a).
  stage_pipe<<<512, 256, 0, stream>>>(W_fc1, W_w, pool, enc, Wfw, Mbuf, Abuf, Qpl, encW,
                                      2, 2,   0, 0,   0, 0,   0);     // 8 chain + 504 encW
  stage_pipe<<<512, 256, 0, stream>>>(W_fc1, W_w, pool, enc, Wfw, Mbuf, Abuf, Qpl, encW,
                                      4, 4,   0, 4,   0, 0,   504);   // 16 + 16 + 480 encW
  stage_pipe<<<512, 256, 0, stream>>>(W_fc1, W_w, pool, enc, Wfw, Mbuf, Abuf, Qpl, encW,
                                      8, 8,   4, 4,   0, 4,   984);   // 32 + 16 + 64 + 400 encW
  stage_pipe<<<392, 256, 0, stream>>>(W_fc1, W_w, pool, enc, Wfw, Mbuf, Abuf, Qpl, encW,
                                      16, 16, 8, 8,   4, 4,   1384);  // 64 + 32 + 64 + 232 encW
  stage_pipe<<<320, 256, 0, stream>>>(W_fc1, W_w, pool, enc, Wfw, Mbuf, Abuf, Qpl, encW,
                                      32, 32, 16, 16, 8, 8,   0);     // 128 + 64 + 128
  stage_pipe<<<640, 256, 0, stream>>>(W_fc1, W_w, pool, enc, Wfw, Mbuf, Abuf, Qpl, encW,
                                      64, 64, 32, 32, 16, 16, 0);     // 256 + 128 + 256
  stage_pipe<<<816, 256, 0, stream>>>(W_fc1, W_w, pool, enc, Wfw, Mbuf, Abuf, Qpl, encW,
                                      128, 12, 64, 64, 32, 32, 0);    // 48 + 256 + 512
  stage_pipe<<<1072, 256, 0, stream>>>(W_fc1, W_w, pool, enc, Wfw, Mbuf, Abuf, Qpl, encW,
                                      0, 0,   128, 12, 64, 64, 0);    // 48 + 1024
  stage_pipe<<<192, 256, 0, stream>>>(W_fc1, W_w, pool, enc, Wfw, Mbuf, Abuf, Qpl, encW,
                                      0, 0,   0, 0,   128, 12, 0);    // 192

  decode_kernel<<<512, 256, 0, stream>>>(enc, W_kk, W_vv, Wc, encW, Qpl, wcapb, cap, dem, out);
}